// Round 1
// baseline (9848.506 us; speedup 1.0000x reference)
//
#include <hip/hip_runtime.h>
#include <math.h>

// Problem constants (from reference)
#define HH   512      // hidden
#define BB   32       // batch
#define TENC 256      // encoder steps
#define TDEC 32       // decoder steps
#define VV   50000    // vocab
#define SOSTOK 2
#define G3H  1536     // 3*H
#define NCG  49       // ceil(50000/1024) logits col-groups
#define SCAN_NBLK 256

__device__ __forceinline__ float sigmoidf_(float x) { return 1.0f / (1.0f + expf(-x)); }

// ---------------------------------------------------------------------------
// Transpose W [1536][512] -> WT [512][1536] (scalar, 32x32 LDS tiles).
// ---------------------------------------------------------------------------
__global__ __launch_bounds__(256) void transpose_w(
    const float* __restrict__ in, float* __restrict__ out)
{
    __shared__ float tile[32][33];
    const int kt = blockIdx.x * 32;   // over HH
    const int jt = blockIdx.y * 32;   // over G3H
    const int tx = threadIdx.x & 31, ty = threadIdx.x >> 5;  // 32 x 8
#pragma unroll
    for (int l = 0; l < 4; l++) {
        int j = jt + ty + l * 8;
        tile[ty + l * 8][tx] = in[(size_t)j * HH + kt + tx];
    }
    __syncthreads();
#pragma unroll
    for (int l = 0; l < 4; l++) {
        int k = kt + ty + l * 8;
        out[(size_t)k * G3H + jt + tx] = tile[tx][ty + l * 8];
    }
}

// ---------------------------------------------------------------------------
// gx kernel (TN, coalesced), 32-row register tile.
// out[m][j] = dot(A_row(m), WT[:,j]) + bias[j]
// Block: 32 rows x 1024 cols. grid = (M/32, 2). LDS As = 64KB -> 2 blocks/CU.
// ---------------------------------------------------------------------------
__global__ __launch_bounds__(256, 2) void gxT_kernel(
    const int* __restrict__ idxs, const float* __restrict__ emb,
    const float* __restrict__ WT, const float* __restrict__ bias,
    float* __restrict__ out, int dec_mode)
{
    __shared__ __align__(16) float As[32][HH];
    const int tid = threadIdx.x;
    const int m0 = blockIdx.x * 32;

    for (int l = tid; l < 32 * HH; l += 256) {
        int r = l >> 9, k = l & (HH - 1);
        int m = m0 + r;
        int t = m >> 5, b = m & 31;
        int idx;
        if (dec_mode) idx = (t == 0) ? SOSTOK : idxs[b * TDEC + (t - 1)];
        else          idx = idxs[b * TENC + t];
        float v = emb[(size_t)idx * HH + k];
        if (dec_mode) v = fmaxf(v, 0.0f);
        As[r][k] = v;
    }
    __syncthreads();

    const int j0 = blockIdx.y * 1024 + tid * 4;
    if (j0 >= G3H) return;   // after syncthreads: safe

    float acc[32][4];
#pragma unroll
    for (int r = 0; r < 32; r++)
#pragma unroll
        for (int jj = 0; jj < 4; jj++) acc[r][jj] = 0.0f;

    for (int kc = 0; kc < HH; kc += 4) {
        float4 w0 = *(const float4*)(WT + (size_t)(kc + 0) * G3H + j0);
        float4 w1 = *(const float4*)(WT + (size_t)(kc + 1) * G3H + j0);
        float4 w2 = *(const float4*)(WT + (size_t)(kc + 2) * G3H + j0);
        float4 w3 = *(const float4*)(WT + (size_t)(kc + 3) * G3H + j0);
#pragma unroll
        for (int r = 0; r < 32; r++) {
            float4 a = *(const float4*)(&As[r][kc]);
            acc[r][0] += a.x * w0.x + a.y * w1.x + a.z * w2.x + a.w * w3.x;
            acc[r][1] += a.x * w0.y + a.y * w1.y + a.z * w2.y + a.w * w3.y;
            acc[r][2] += a.x * w0.z + a.y * w1.z + a.z * w2.z + a.w * w3.z;
            acc[r][3] += a.x * w0.w + a.y * w1.w + a.z * w2.w + a.w * w3.w;
        }
    }

    float4 bv = *(const float4*)(bias + j0);
#pragma unroll
    for (int r = 0; r < 32; r++) {
        float4 o;
        o.x = acc[r][0] + bv.x;
        o.y = acc[r][1] + bv.y;
        o.z = acc[r][2] + bv.z;
        o.w = acc[r][3] + bv.w;
        *(float4*)(out + (size_t)(m0 + r) * G3H + j0) = o;
    }
}

// ---------------------------------------------------------------------------
// Persistent GRU scan: ONE kernel does all 256 encoder + 32 decoder steps.
// 256 blocks x 256 threads, guaranteed co-resident (1 block/CU).
// Each block owns 2 hidden units (i0, i0+1): weights for all 3 gates of BOTH
// enc and dec models live in LDS for the whole kernel (26KB, stride-68 pad ->
// conflict-free broadcast reads). Per step: grid-wide sense-reversing barrier.
// Thread map: b = tid>>3 (batch), kq = tid&7 (64-wide k-chunk).
// ---------------------------------------------------------------------------
__device__ __forceinline__ void grid_sync(unsigned* bar)
{
    __syncthreads();
    if (threadIdx.x == 0) {
        __threadfence();  // release: push this block's h writes device-wide
        unsigned my = __hip_atomic_load(&bar[1], __ATOMIC_RELAXED, __HIP_MEMORY_SCOPE_AGENT);
        unsigned prev = __hip_atomic_fetch_add(&bar[0], 1u, __ATOMIC_ACQ_REL, __HIP_MEMORY_SCOPE_AGENT);
        if (prev == SCAN_NBLK - 1) {
            __hip_atomic_store(&bar[0], 0u, __ATOMIC_RELAXED, __HIP_MEMORY_SCOPE_AGENT);
            __hip_atomic_fetch_add(&bar[1], 1u, __ATOMIC_ACQ_REL, __HIP_MEMORY_SCOPE_AGENT);
        } else {
            while (__hip_atomic_load(&bar[1], __ATOMIC_RELAXED, __HIP_MEMORY_SCOPE_AGENT) == my)
                __builtin_amdgcn_s_sleep(1);
        }
        __threadfence();  // acquire: invalidate stale cached h lines
    }
    __syncthreads();
}

__device__ __forceinline__ void gru_step(
    const float* __restrict__ wm,      // &wlds[model], layout [g*2+il][544]
    const float* __restrict__ bh,      // 6 biases [g*2+il]
    const float* __restrict__ gx_t,    // [BB][G3H] for this step (incl. bih)
    const float* __restrict__ h_in,    // [BB][HH]
    float* __restrict__ h_out,         // [BB][HH]
    int b, int kq, int i0)
{
    // prefetch the scalars the tail needs (independent of the dot loop)
    float p0=0,p1=0,p2=0,p3=0,p4=0,p5=0,p6=0,p7=0;
    if (kq == 0) {
        p0 = gx_t[b * G3H + i0];          p1 = gx_t[b * G3H + i0 + 1];
        p2 = gx_t[b * G3H + 512 + i0];    p3 = gx_t[b * G3H + 512 + i0 + 1];
        p4 = gx_t[b * G3H + 1024 + i0];   p5 = gx_t[b * G3H + 1024 + i0 + 1];
        p6 = h_in[b * HH + i0];           p7 = h_in[b * HH + i0 + 1];
    }

    const float* hp  = h_in + b * HH + kq * 64;
    const float* w00 = wm + 0 * 544 + kq * 68;   // r, il0
    const float* w01 = wm + 1 * 544 + kq * 68;   // r, il1
    const float* w10 = wm + 2 * 544 + kq * 68;   // z, il0
    const float* w11 = wm + 3 * 544 + kq * 68;   // z, il1
    const float* w20 = wm + 4 * 544 + kq * 68;   // n, il0
    const float* w21 = wm + 5 * 544 + kq * 68;   // n, il1

    float ar0 = 0.f, ar1 = 0.f, az0 = 0.f, az1 = 0.f, an0 = 0.f, an1 = 0.f;
#pragma unroll
    for (int c = 0; c < 16; c++) {
        float4 h4 = *(const float4*)(hp + c * 4);
        float4 w;
        w = *(const float4*)(w00 + c * 4); ar0 += h4.x*w.x + h4.y*w.y + h4.z*w.z + h4.w*w.w;
        w = *(const float4*)(w01 + c * 4); ar1 += h4.x*w.x + h4.y*w.y + h4.z*w.z + h4.w*w.w;
        w = *(const float4*)(w10 + c * 4); az0 += h4.x*w.x + h4.y*w.y + h4.z*w.z + h4.w*w.w;
        w = *(const float4*)(w11 + c * 4); az1 += h4.x*w.x + h4.y*w.y + h4.z*w.z + h4.w*w.w;
        w = *(const float4*)(w20 + c * 4); an0 += h4.x*w.x + h4.y*w.y + h4.z*w.z + h4.w*w.w;
        w = *(const float4*)(w21 + c * 4); an1 += h4.x*w.x + h4.y*w.y + h4.z*w.z + h4.w*w.w;
    }
    // reduce across the 8 k-chunks (lane bits 0..2)
    ar0 += __shfl_xor(ar0, 1); ar0 += __shfl_xor(ar0, 2); ar0 += __shfl_xor(ar0, 4);
    ar1 += __shfl_xor(ar1, 1); ar1 += __shfl_xor(ar1, 2); ar1 += __shfl_xor(ar1, 4);
    az0 += __shfl_xor(az0, 1); az0 += __shfl_xor(az0, 2); az0 += __shfl_xor(az0, 4);
    az1 += __shfl_xor(az1, 1); az1 += __shfl_xor(az1, 2); az1 += __shfl_xor(az1, 4);
    an0 += __shfl_xor(an0, 1); an0 += __shfl_xor(an0, 2); an0 += __shfl_xor(an0, 4);
    an1 += __shfl_xor(an1, 1); an1 += __shfl_xor(an1, 2); an1 += __shfl_xor(an1, 4);

    if (kq == 0) {
        float r0 = sigmoidf_(p0 + ar0 + bh[0]);
        float z0 = sigmoidf_(p2 + az0 + bh[2]);
        float n0 = tanhf    (p4 + r0 * (an0 + bh[4]));
        h_out[b * HH + i0]     = (1.0f - z0) * n0 + z0 * p6;
        float r1 = sigmoidf_(p1 + ar1 + bh[1]);
        float z1 = sigmoidf_(p3 + az1 + bh[3]);
        float n1 = tanhf    (p5 + r1 * (an1 + bh[5]));
        h_out[b * HH + i0 + 1] = (1.0f - z1) * n1 + z1 * p7;
    }
}

__global__ __launch_bounds__(256, 1) void scan_kernel(
    const float* __restrict__ Whh_e, const float* __restrict__ bhh_e,
    const float* __restrict__ Whh_d, const float* __restrict__ bhh_d,
    const float* __restrict__ gx_enc, const float* __restrict__ gx_dec,
    float* __restrict__ hb0, float* __restrict__ hb1,
    float* __restrict__ h_all, unsigned* __restrict__ bar)
{
    // [model][g*2+il][8 kq][68 floats (64 used, +4 pad -> conflict-free)]
    __shared__ __align__(16) float wlds[2][6][544];
    const int tid = threadIdx.x;
    const int bid = blockIdx.x;
    const int b   = tid >> 3;
    const int kq  = tid & 7;
    const int i0  = bid * 2;

    // Stage both models' weight slices (coalesced global reads)
#pragma unroll
    for (int m = 0; m < 2; m++) {
        const float* W = m ? Whh_d : Whh_e;
#pragma unroll
        for (int g = 0; g < 3; g++)
#pragma unroll
            for (int il = 0; il < 2; il++) {
                const float* src = W + (size_t)(g * 512 + i0 + il) * 512;
                for (int k = tid; k < 512; k += 256)
                    wlds[m][g * 2 + il][(k >> 6) * 68 + (k & 63)] = src[k];
            }
    }
    float bhE[6], bhD[6];
#pragma unroll
    for (int g = 0; g < 3; g++)
#pragma unroll
        for (int il = 0; il < 2; il++) {
            bhE[g * 2 + il] = bhh_e[g * 512 + i0 + il];
            bhD[g * 2 + il] = bhh_d[g * 512 + i0 + il];
        }
    __syncthreads();

    // Encoder: 256 steps, ping-pong hb0/hb1 (h0 = hb0, zeroed by host memset)
    for (int t = 0; t < TENC; t++) {
        const float* hin = (t & 1) ? hb1 : hb0;
        float*       hout = (t & 1) ? hb0 : hb1;
        gru_step(&wlds[0][0][0], bhE, gx_enc + (size_t)t * BB * G3H, hin, hout, b, kq, i0);
        grid_sync(bar);
    }
    // TENC even -> h_enc in hb0

    // Decoder: 32 steps, write every h_t into h_all
    for (int t = 0; t < TDEC; t++) {
        const float* hin = (t == 0) ? hb0 : (h_all + (size_t)(t - 1) * BB * HH);
        float*       hout = h_all + (size_t)t * BB * HH;
        gru_step(&wlds[1][0][0], bhD, gx_dec + (size_t)t * BB * G3H, hin, hout, b, kq, i0);
        if (t < TDEC - 1) grid_sync(bar);
    }
}

// ---------------------------------------------------------------------------
// Fused logits GEMM + per-row partial logsumexp + target-logit gather.
// 32-row register tile (acc = 128 VGPR), As = 64KB LDS -> 2 blocks/CU.
// grid = (1024/32 = 32, NCG).
// ---------------------------------------------------------------------------
__global__ __launch_bounds__(256, 2) void logits_kernel(
    const float* __restrict__ Hall,   // [1024][512]
    const float* __restrict__ Wg,     // [512][50000]
    const float* __restrict__ bg,     // [50000]
    const int* __restrict__ qw,       // [32][32] targets
    float* __restrict__ pmax,         // [49][1024]
    float* __restrict__ psum,         // [49][1024]
    float* __restrict__ tgt_logit)    // [1024]
{
    __shared__ __align__(16) float As[32][HH];   // 64KB; reused as wred after GEMM
    const int tid = threadIdx.x;
    const int m0 = blockIdx.x * 32;
    const int lane = tid & 63, wid = tid >> 6;

    for (int l = tid; l < 32 * HH; l += 256) {
        int r = l >> 9, k = l & (HH - 1);
        As[r][k] = Hall[(size_t)(m0 + r) * HH + k];
    }
    __syncthreads();

    const int j0 = blockIdx.y * 1024 + tid * 4;
    const bool valid = (j0 < VV);

    float acc[32][4];
#pragma unroll
    for (int r = 0; r < 32; r++)
#pragma unroll
        for (int jj = 0; jj < 4; jj++) acc[r][jj] = 0.0f;

    if (valid) {
        for (int kc = 0; kc < HH; kc += 4) {
            float4 w0 = *(const float4*)(Wg + (size_t)(kc + 0) * VV + j0);
            float4 w1 = *(const float4*)(Wg + (size_t)(kc + 1) * VV + j0);
            float4 w2 = *(const float4*)(Wg + (size_t)(kc + 2) * VV + j0);
            float4 w3 = *(const float4*)(Wg + (size_t)(kc + 3) * VV + j0);
#pragma unroll
            for (int r = 0; r < 32; r++) {
                float4 a = *(const float4*)(&As[r][kc]);
                acc[r][0] += a.x * w0.x + a.y * w1.x + a.z * w2.x + a.w * w3.x;
                acc[r][1] += a.x * w0.y + a.y * w1.y + a.z * w2.y + a.w * w3.y;
                acc[r][2] += a.x * w0.z + a.y * w1.z + a.z * w2.z + a.w * w3.z;
                acc[r][3] += a.x * w0.w + a.y * w1.w + a.z * w2.w + a.w * w3.w;
            }
        }
        float4 bv = *(const float4*)(bg + j0);
#pragma unroll
        for (int r = 0; r < 32; r++) {
            acc[r][0] += bv.x; acc[r][1] += bv.y; acc[r][2] += bv.z; acc[r][3] += bv.w;
        }
#pragma unroll
        for (int r = 0; r < 32; r++) {
            int m = m0 + r, t = m >> 5, bb = m & 31;
            int tj = qw[bb * TDEC + t];
            if (tj >= j0 && tj < j0 + 4) tgt_logit[m] = acc[r][tj - j0];
        }
    }

    __syncthreads();                 // As no longer needed by anyone
    float* wredf = &As[0][0];        // reuse as wred[32][4]

    float rowmax[32];
#pragma unroll
    for (int r = 0; r < 32; r++) {
        float v = valid ? fmaxf(fmaxf(acc[r][0], acc[r][1]), fmaxf(acc[r][2], acc[r][3]))
                        : -INFINITY;
        for (int off = 32; off > 0; off >>= 1) v = fmaxf(v, __shfl_xor(v, off));
        if (lane == 0) wredf[r * 4 + wid] = v;
    }
    __syncthreads();
#pragma unroll
    for (int r = 0; r < 32; r++)
        rowmax[r] = fmaxf(fmaxf(wredf[r * 4 + 0], wredf[r * 4 + 1]),
                          fmaxf(wredf[r * 4 + 2], wredf[r * 4 + 3]));
    if (tid == 0) {
#pragma unroll
        for (int r = 0; r < 32; r++) pmax[blockIdx.y * 1024 + m0 + r] = rowmax[r];
    }
    __syncthreads();

#pragma unroll
    for (int r = 0; r < 32; r++) {
        float s = 0.0f;
        if (valid) {
            s = expf(acc[r][0] - rowmax[r]) + expf(acc[r][1] - rowmax[r])
              + expf(acc[r][2] - rowmax[r]) + expf(acc[r][3] - rowmax[r]);
        }
        for (int off = 32; off > 0; off >>= 1) s += __shfl_xor(s, off);
        if (lane == 0) wredf[r * 4 + wid] = s;
    }
    __syncthreads();

    if (tid < 32) {
        float S = wredf[tid * 4 + 0] + wredf[tid * 4 + 1]
                + wredf[tid * 4 + 2] + wredf[tid * 4 + 3];
        psum[blockIdx.y * 1024 + m0 + tid] = S;
    }
}

// ---------------------------------------------------------------------------
// Combine col-group partials -> per-row lse -> loss = sum(lse - tgt)/Tdec
// ---------------------------------------------------------------------------
__global__ __launch_bounds__(256) void loss_kernel(
    const float* __restrict__ pmax, const float* __restrict__ psum,
    const float* __restrict__ tgt_logit, float* __restrict__ out)
{
    const int tid = threadIdx.x;
    float local = 0.0f;
    for (int m = tid; m < 1024; m += 256) {
        float M = -INFINITY;
        for (int cg = 0; cg < NCG; cg++) M = fmaxf(M, pmax[cg * 1024 + m]);
        float S = 0.0f;
        for (int cg = 0; cg < NCG; cg++) S += psum[cg * 1024 + m] * expf(pmax[cg * 1024 + m] - M);
        local += M + logf(S) - tgt_logit[m];
    }
    __shared__ float red[256];
    red[tid] = local;
    __syncthreads();
    for (int s = 128; s > 0; s >>= 1) {
        if (tid < s) red[tid] += red[tid + s];
        __syncthreads();
    }
    if (tid == 0) out[0] = red[0] / (float)TDEC;
}

// ---------------------------------------------------------------------------
extern "C" void kernel_launch(void* const* d_in, const int* in_sizes, int n_in,
                              void* d_out, int out_size, void* d_ws, size_t ws_size,
                              hipStream_t stream)
{
    const int*   cw     = (const int*)  d_in[0];
    const int*   qw     = (const int*)  d_in[1];
    const float* emb_e  = (const float*)d_in[2];
    const float* emb_d  = (const float*)d_in[3];
    const float* Wih_e  = (const float*)d_in[4];
    const float* Whh_e  = (const float*)d_in[5];
    const float* bih_e  = (const float*)d_in[6];
    const float* bhh_e  = (const float*)d_in[7];
    const float* Wih_d  = (const float*)d_in[8];
    const float* Whh_d  = (const float*)d_in[9];
    const float* bih_d  = (const float*)d_in[10];
    const float* bhh_d  = (const float*)d_in[11];
    const float* Wg     = (const float*)d_in[12];
    const float* bg     = (const float*)d_in[13];

    // Workspace layout (floats); total ~65 MB
    float* ws      = (float*)d_ws;
    float* gx_enc  = ws;                                   // 8192*1536
    float* gx_dec  = gx_enc + (size_t)8192 * G3H;          // 1024*1536
    float* hbuf0   = gx_dec + (size_t)1024 * G3H;          // 32*512
    float* hbuf1   = hbuf0 + BB * HH;                      // 32*512
    float* h_all   = hbuf1 + BB * HH;                      // 1024*512
    float* pmax    = h_all + (size_t)1024 * HH;            // 49*1024
    float* psum    = pmax + NCG * 1024;                    // 49*1024
    float* tgt_l   = psum + NCG * 1024;                    // 1024
    float* WihT_e  = tgt_l + 1024;                         // 512*1536
    float* WihT_d  = WihT_e + (size_t)HH * G3H;            // 512*1536
    unsigned* bar  = (unsigned*)(WihT_d + (size_t)HH * G3H);  // 2 x u32

    // h0 = 0; barrier state = 0
    hipMemsetAsync(hbuf0, 0, BB * HH * sizeof(float), stream);
    hipMemsetAsync(bar, 0, 2 * sizeof(unsigned), stream);

    // Phase 0: weight transposes for the gx GEMMs
    transpose_w<<<dim3(16, 48), 256, 0, stream>>>(Wih_e, WihT_e);
    transpose_w<<<dim3(16, 48), 256, 0, stream>>>(Wih_d, WihT_d);

    // Phase 1: encoder + decoder gx (all timesteps in parallel)
    gxT_kernel<<<dim3(256, 2), 256, 0, stream>>>(cw, emb_e, WihT_e, bih_e, gx_enc, 0);
    gxT_kernel<<<dim3(32, 2),  256, 0, stream>>>(qw, emb_d, WihT_d, bih_d, gx_dec, 1);

    // Phase 2+4: the entire sequential scan (enc 256 + dec 32 steps) in ONE
    // persistent kernel with a device-scope grid barrier per step.
    scan_kernel<<<SCAN_NBLK, 256, 0, stream>>>(
        Whh_e, bhh_e, Whh_d, bhh_d, gx_enc, gx_dec, hbuf0, hbuf1, h_all, bar);

    // Phase 5: batched logits + online logsumexp partials (one big GEMM)
    logits_kernel<<<dim3(32, NCG), 256, 0, stream>>>(h_all, Wg, bg, qw, pmax, psum, tgt_l);

    // Phase 6: combine partials -> scalar loss
    loss_kernel<<<1, 256, 0, stream>>>(pmax, psum, tgt_l, (float*)d_out);
}

// Round 2
// 5801.630 us; speedup vs baseline: 1.6975x; 1.6975x over previous
//
#include <hip/hip_runtime.h>
#include <math.h>

// Problem constants (from reference)
#define HH   512      // hidden
#define BB   32       // batch
#define TENC 256      // encoder steps
#define TDEC 32       // decoder steps
#define VV   50000    // vocab
#define SOSTOK 2
#define G3H  1536     // 3*H
#define NCG  49       // ceil(50000/1024) logits col-groups
#define SCAN_NBLK 256

typedef unsigned long long u64;

__device__ __forceinline__ float sigmoidf_(float x) { return 1.0f / (1.0f + expf(-x)); }

// Coherent (cross-XCD) 8-byte h accesses: relaxed agent-scope atomics compile
// to sc0/sc1-flagged global loads/stores that bypass L1 + per-XCD L2 and are
// served by the coherent Infinity Cache. No cache-maintenance instructions.
__device__ __forceinline__ float2 ld_h2(const float* p) {
    u64 u = __hip_atomic_load((const u64*)p, __ATOMIC_RELAXED, __HIP_MEMORY_SCOPE_AGENT);
    union { u64 u; float2 f; } c; c.u = u; return c.f;
}
__device__ __forceinline__ void st_h2(float* p, float2 v) {
    union { u64 u; float2 f; } c; c.f = v;
    __hip_atomic_store((u64*)p, c.u, __ATOMIC_RELAXED, __HIP_MEMORY_SCOPE_AGENT);
}

// ---------------------------------------------------------------------------
// Transpose W [1536][512] -> WT [512][1536] (scalar, 32x32 LDS tiles).
// ---------------------------------------------------------------------------
__global__ __launch_bounds__(256) void transpose_w(
    const float* __restrict__ in, float* __restrict__ out)
{
    __shared__ float tile[32][33];
    const int kt = blockIdx.x * 32;   // over HH
    const int jt = blockIdx.y * 32;   // over G3H
    const int tx = threadIdx.x & 31, ty = threadIdx.x >> 5;  // 32 x 8
#pragma unroll
    for (int l = 0; l < 4; l++) {
        int j = jt + ty + l * 8;
        tile[ty + l * 8][tx] = in[(size_t)j * HH + kt + tx];
    }
    __syncthreads();
#pragma unroll
    for (int l = 0; l < 4; l++) {
        int k = kt + ty + l * 8;
        out[(size_t)k * G3H + jt + tx] = tile[tx][ty + l * 8];
    }
}

// ---------------------------------------------------------------------------
// gx kernel (TN, coalesced), 32-row register tile.
// out[m][j] = dot(A_row(m), WT[:,j]) + bias[j]
// Block: 32 rows x 1024 cols. grid = (M/32, 2). LDS As = 64KB -> 2 blocks/CU.
// ---------------------------------------------------------------------------
__global__ __launch_bounds__(256, 2) void gxT_kernel(
    const int* __restrict__ idxs, const float* __restrict__ emb,
    const float* __restrict__ WT, const float* __restrict__ bias,
    float* __restrict__ out, int dec_mode)
{
    __shared__ __align__(16) float As[32][HH];
    const int tid = threadIdx.x;
    const int m0 = blockIdx.x * 32;

    for (int l = tid; l < 32 * HH; l += 256) {
        int r = l >> 9, k = l & (HH - 1);
        int m = m0 + r;
        int t = m >> 5, b = m & 31;
        int idx;
        if (dec_mode) idx = (t == 0) ? SOSTOK : idxs[b * TDEC + (t - 1)];
        else          idx = idxs[b * TENC + t];
        float v = emb[(size_t)idx * HH + k];
        if (dec_mode) v = fmaxf(v, 0.0f);
        As[r][k] = v;
    }
    __syncthreads();

    const int j0 = blockIdx.y * 1024 + tid * 4;
    if (j0 >= G3H) return;   // after syncthreads: safe

    float acc[32][4];
#pragma unroll
    for (int r = 0; r < 32; r++)
#pragma unroll
        for (int jj = 0; jj < 4; jj++) acc[r][jj] = 0.0f;

    for (int kc = 0; kc < HH; kc += 4) {
        float4 w0 = *(const float4*)(WT + (size_t)(kc + 0) * G3H + j0);
        float4 w1 = *(const float4*)(WT + (size_t)(kc + 1) * G3H + j0);
        float4 w2 = *(const float4*)(WT + (size_t)(kc + 2) * G3H + j0);
        float4 w3 = *(const float4*)(WT + (size_t)(kc + 3) * G3H + j0);
#pragma unroll
        for (int r = 0; r < 32; r++) {
            float4 a = *(const float4*)(&As[r][kc]);
            acc[r][0] += a.x * w0.x + a.y * w1.x + a.z * w2.x + a.w * w3.x;
            acc[r][1] += a.x * w0.y + a.y * w1.y + a.z * w2.y + a.w * w3.y;
            acc[r][2] += a.x * w0.z + a.y * w1.z + a.z * w2.z + a.w * w3.z;
            acc[r][3] += a.x * w0.w + a.y * w1.w + a.z * w2.w + a.w * w3.w;
        }
    }

    float4 bv = *(const float4*)(bias + j0);
#pragma unroll
    for (int r = 0; r < 32; r++) {
        float4 o;
        o.x = acc[r][0] + bv.x;
        o.y = acc[r][1] + bv.y;
        o.z = acc[r][2] + bv.z;
        o.w = acc[r][3] + bv.w;
        *(float4*)(out + (size_t)(m0 + r) * G3H + j0) = o;
    }
}

// ---------------------------------------------------------------------------
// Grid barrier, fence-free. Monotonic counters, 2-level tree:
//   bar[0]          = sense (step counter)
//   bar[32]         = root  (counts completed groups, 8 per step)
//   bar[64 + g*32]  = leaf g (g = bid&7; 32 blocks/group)
// Leaf add uses RELEASE (orders the drained sc1 h-stores; L2 is clean so the
// implied writeback is cheap). Everything else RELAXED: spin freshness comes
// from atomic coherence of the flag line; h freshness from sc1 atomic loads.
// No buffer_inv anywhere -> L2 stays warm for gx/weights all 288 steps.
// ---------------------------------------------------------------------------
__device__ __forceinline__ void grid_sync(unsigned* bar, unsigned cnt)
{
    __syncthreads();   // all waves drain vmcnt (h stores complete) before this
    if (threadIdx.x == 0) {
        unsigned* leaf = bar + 64 + (blockIdx.x & 7) * 32;
        unsigned prev = __hip_atomic_fetch_add(leaf, 1u, __ATOMIC_RELEASE,
                                               __HIP_MEMORY_SCOPE_AGENT);
        if ((prev & 31) == 31) {   // 32nd arrival of this group this step
            unsigned rp = __hip_atomic_fetch_add(bar + 32, 1u, __ATOMIC_RELAXED,
                                                 __HIP_MEMORY_SCOPE_AGENT);
            if ((rp & 7) == 7)     // last group: flip sense
                __hip_atomic_fetch_add(bar, 1u, __ATOMIC_RELAXED,
                                       __HIP_MEMORY_SCOPE_AGENT);
        }
        while (__hip_atomic_load(bar, __ATOMIC_RELAXED,
                                 __HIP_MEMORY_SCOPE_AGENT) < cnt)
            __builtin_amdgcn_s_sleep(1);
    }
    __syncthreads();
}

// ---------------------------------------------------------------------------
// One GRU step inside the persistent kernel. Thread map: b = tid>>3 (batch),
// kq = tid&7 (64-float k-chunk). Weights live in LDS for the whole scan; h is
// exchanged through the coherent path (ld_h2/st_h2).
// ---------------------------------------------------------------------------
__device__ __forceinline__ void gru_step(
    const float* __restrict__ wm,      // &wlds[model], layout [g*2+il][544]
    const float* __restrict__ bh,      // 6 biases [g*2+il]
    const float* __restrict__ gx_t,    // [BB][G3H] for this step (incl. bih)
    const float* __restrict__ h_in,    // [BB][HH]
    float* __restrict__ h_out,         // [BB][HH]
    int b, int kq, int i0)
{
    // prefetch the scalars the tail needs (independent of the dot loop)
    float p0=0,p1=0,p2=0,p3=0,p4=0,p5=0,p6=0,p7=0;
    if (kq == 0) {
        p0 = gx_t[b * G3H + i0];          p1 = gx_t[b * G3H + i0 + 1];
        p2 = gx_t[b * G3H + 512 + i0];    p3 = gx_t[b * G3H + 512 + i0 + 1];
        p4 = gx_t[b * G3H + 1024 + i0];   p5 = gx_t[b * G3H + 1024 + i0 + 1];
        float2 hp2 = ld_h2(h_in + b * HH + i0);
        p6 = hp2.x;                        p7 = hp2.y;
    }

    const float* hp  = h_in + b * HH + kq * 64;
    const float* w00 = wm + 0 * 544 + kq * 68;   // r, il0
    const float* w01 = wm + 1 * 544 + kq * 68;   // r, il1
    const float* w10 = wm + 2 * 544 + kq * 68;   // z, il0
    const float* w11 = wm + 3 * 544 + kq * 68;   // z, il1
    const float* w20 = wm + 4 * 544 + kq * 68;   // n, il0
    const float* w21 = wm + 5 * 544 + kq * 68;   // n, il1

    float ar0 = 0.f, ar1 = 0.f, az0 = 0.f, az1 = 0.f, an0 = 0.f, an1 = 0.f;
#pragma unroll
    for (int c = 0; c < 16; c++) {
        float2 ha = ld_h2(hp + c * 4);
        float2 hb2 = ld_h2(hp + c * 4 + 2);
        float4 w;
        w = *(const float4*)(w00 + c * 4);
        ar0 += ha.x*w.x + ha.y*w.y + hb2.x*w.z + hb2.y*w.w;
        w = *(const float4*)(w01 + c * 4);
        ar1 += ha.x*w.x + ha.y*w.y + hb2.x*w.z + hb2.y*w.w;
        w = *(const float4*)(w10 + c * 4);
        az0 += ha.x*w.x + ha.y*w.y + hb2.x*w.z + hb2.y*w.w;
        w = *(const float4*)(w11 + c * 4);
        az1 += ha.x*w.x + ha.y*w.y + hb2.x*w.z + hb2.y*w.w;
        w = *(const float4*)(w20 + c * 4);
        an0 += ha.x*w.x + ha.y*w.y + hb2.x*w.z + hb2.y*w.w;
        w = *(const float4*)(w21 + c * 4);
        an1 += ha.x*w.x + ha.y*w.y + hb2.x*w.z + hb2.y*w.w;
    }
    // reduce across the 8 k-chunks (lane bits 0..2)
    ar0 += __shfl_xor(ar0, 1); ar0 += __shfl_xor(ar0, 2); ar0 += __shfl_xor(ar0, 4);
    ar1 += __shfl_xor(ar1, 1); ar1 += __shfl_xor(ar1, 2); ar1 += __shfl_xor(ar1, 4);
    az0 += __shfl_xor(az0, 1); az0 += __shfl_xor(az0, 2); az0 += __shfl_xor(az0, 4);
    az1 += __shfl_xor(az1, 1); az1 += __shfl_xor(az1, 2); az1 += __shfl_xor(az1, 4);
    an0 += __shfl_xor(an0, 1); an0 += __shfl_xor(an0, 2); an0 += __shfl_xor(an0, 4);
    an1 += __shfl_xor(an1, 1); an1 += __shfl_xor(an1, 2); an1 += __shfl_xor(an1, 4);

    if (kq == 0) {
        float r0 = sigmoidf_(p0 + ar0 + bh[0]);
        float z0 = sigmoidf_(p2 + az0 + bh[2]);
        float n0 = tanhf    (p4 + r0 * (an0 + bh[4]));
        float r1 = sigmoidf_(p1 + ar1 + bh[1]);
        float z1 = sigmoidf_(p3 + az1 + bh[3]);
        float n1 = tanhf    (p5 + r1 * (an1 + bh[5]));
        float2 o;
        o.x = (1.0f - z0) * n0 + z0 * p6;
        o.y = (1.0f - z1) * n1 + z1 * p7;
        st_h2(h_out + b * HH + i0, o);
    }
}

__global__ __launch_bounds__(256, 1) void scan_kernel(
    const float* __restrict__ Whh_e, const float* __restrict__ bhh_e,
    const float* __restrict__ Whh_d, const float* __restrict__ bhh_d,
    const float* __restrict__ gx_enc, const float* __restrict__ gx_dec,
    float* __restrict__ hb0, float* __restrict__ hb1,
    float* __restrict__ h_all, unsigned* __restrict__ bar)
{
    // [model][g*2+il][8 kq][68 floats (64 used, +4 pad -> conflict-free)]
    __shared__ __align__(16) float wlds[2][6][544];
    const int tid = threadIdx.x;
    const int bid = blockIdx.x;
    const int b   = tid >> 3;
    const int kq  = tid & 7;
    const int i0  = bid * 2;

    // Stage both models' weight slices (coalesced global reads)
#pragma unroll
    for (int m = 0; m < 2; m++) {
        const float* W = m ? Whh_d : Whh_e;
#pragma unroll
        for (int g = 0; g < 3; g++)
#pragma unroll
            for (int il = 0; il < 2; il++) {
                const float* src = W + (size_t)(g * 512 + i0 + il) * 512;
                for (int k = tid; k < 512; k += 256)
                    wlds[m][g * 2 + il][(k >> 6) * 68 + (k & 63)] = src[k];
            }
    }
    float bhE[6], bhD[6];
#pragma unroll
    for (int g = 0; g < 3; g++)
#pragma unroll
        for (int il = 0; il < 2; il++) {
            bhE[g * 2 + il] = bhh_e[g * 512 + i0 + il];
            bhD[g * 2 + il] = bhh_d[g * 512 + i0 + il];
        }
    __syncthreads();

    unsigned sync_no = 0;

    // Encoder: 256 steps, ping-pong hb0/hb1 (h0 = hb0, zeroed by host memset)
    for (int t = 0; t < TENC; t++) {
        const float* hin = (t & 1) ? hb1 : hb0;
        float*       hout = (t & 1) ? hb0 : hb1;
        gru_step(&wlds[0][0][0], bhE, gx_enc + (size_t)t * BB * G3H, hin, hout, b, kq, i0);
        grid_sync(bar, ++sync_no);
    }
    // TENC even -> h_enc in hb0

    // Decoder: 32 steps, write every h_t into h_all
    for (int t = 0; t < TDEC; t++) {
        const float* hin = (t == 0) ? hb0 : (h_all + (size_t)(t - 1) * BB * HH);
        float*       hout = h_all + (size_t)t * BB * HH;
        gru_step(&wlds[1][0][0], bhD, gx_dec + (size_t)t * BB * G3H, hin, hout, b, kq, i0);
        if (t < TDEC - 1) grid_sync(bar, ++sync_no);
    }
}

// ---------------------------------------------------------------------------
// Fused logits GEMM + per-row partial logsumexp + target-logit gather.
// 32-row register tile (acc = 128 VGPR), As = 64KB LDS -> 2 blocks/CU.
// grid = (1024/32 = 32, NCG).
// ---------------------------------------------------------------------------
__global__ __launch_bounds__(256, 2) void logits_kernel(
    const float* __restrict__ Hall,   // [1024][512]
    const float* __restrict__ Wg,     // [512][50000]
    const float* __restrict__ bg,     // [50000]
    const int* __restrict__ qw,       // [32][32] targets
    float* __restrict__ pmax,         // [49][1024]
    float* __restrict__ psum,         // [49][1024]
    float* __restrict__ tgt_logit)    // [1024]
{
    __shared__ __align__(16) float As[32][HH];   // 64KB; reused as wred after GEMM
    const int tid = threadIdx.x;
    const int m0 = blockIdx.x * 32;
    const int lane = tid & 63, wid = tid >> 6;

    for (int l = tid; l < 32 * HH; l += 256) {
        int r = l >> 9, k = l & (HH - 1);
        As[r][k] = Hall[(size_t)(m0 + r) * HH + k];
    }
    __syncthreads();

    const int j0 = blockIdx.y * 1024 + tid * 4;
    const bool valid = (j0 < VV);

    float acc[32][4];
#pragma unroll
    for (int r = 0; r < 32; r++)
#pragma unroll
        for (int jj = 0; jj < 4; jj++) acc[r][jj] = 0.0f;

    if (valid) {
        for (int kc = 0; kc < HH; kc += 4) {
            float4 w0 = *(const float4*)(Wg + (size_t)(kc + 0) * VV + j0);
            float4 w1 = *(const float4*)(Wg + (size_t)(kc + 1) * VV + j0);
            float4 w2 = *(const float4*)(Wg + (size_t)(kc + 2) * VV + j0);
            float4 w3 = *(const float4*)(Wg + (size_t)(kc + 3) * VV + j0);
#pragma unroll
            for (int r = 0; r < 32; r++) {
                float4 a = *(const float4*)(&As[r][kc]);
                acc[r][0] += a.x * w0.x + a.y * w1.x + a.z * w2.x + a.w * w3.x;
                acc[r][1] += a.x * w0.y + a.y * w1.y + a.z * w2.y + a.w * w3.y;
                acc[r][2] += a.x * w0.z + a.y * w1.z + a.z * w2.z + a.w * w3.z;
                acc[r][3] += a.x * w0.w + a.y * w1.w + a.z * w2.w + a.w * w3.w;
            }
        }
        float4 bv = *(const float4*)(bg + j0);
#pragma unroll
        for (int r = 0; r < 32; r++) {
            acc[r][0] += bv.x; acc[r][1] += bv.y; acc[r][2] += bv.z; acc[r][3] += bv.w;
        }
#pragma unroll
        for (int r = 0; r < 32; r++) {
            int m = m0 + r, t = m >> 5, bb = m & 31;
            int tj = qw[bb * TDEC + t];
            if (tj >= j0 && tj < j0 + 4) tgt_logit[m] = acc[r][tj - j0];
        }
    }

    __syncthreads();                 // As no longer needed by anyone
    float* wredf = &As[0][0];        // reuse as wred[32][4]

    float rowmax[32];
#pragma unroll
    for (int r = 0; r < 32; r++) {
        float v = valid ? fmaxf(fmaxf(acc[r][0], acc[r][1]), fmaxf(acc[r][2], acc[r][3]))
                        : -INFINITY;
        for (int off = 32; off > 0; off >>= 1) v = fmaxf(v, __shfl_xor(v, off));
        if (lane == 0) wredf[r * 4 + wid] = v;
    }
    __syncthreads();
#pragma unroll
    for (int r = 0; r < 32; r++)
        rowmax[r] = fmaxf(fmaxf(wredf[r * 4 + 0], wredf[r * 4 + 1]),
                          fmaxf(wredf[r * 4 + 2], wredf[r * 4 + 3]));
    if (tid == 0) {
#pragma unroll
        for (int r = 0; r < 32; r++) pmax[blockIdx.y * 1024 + m0 + r] = rowmax[r];
    }
    __syncthreads();

#pragma unroll
    for (int r = 0; r < 32; r++) {
        float s = 0.0f;
        if (valid) {
            s = expf(acc[r][0] - rowmax[r]) + expf(acc[r][1] - rowmax[r])
              + expf(acc[r][2] - rowmax[r]) + expf(acc[r][3] - rowmax[r]);
        }
        for (int off = 32; off > 0; off >>= 1) s += __shfl_xor(s, off);
        if (lane == 0) wredf[r * 4 + wid] = s;
    }
    __syncthreads();

    if (tid < 32) {
        float S = wredf[tid * 4 + 0] + wredf[tid * 4 + 1]
                + wredf[tid * 4 + 2] + wredf[tid * 4 + 3];
        psum[blockIdx.y * 1024 + m0 + tid] = S;
    }
}

// ---------------------------------------------------------------------------
// Combine col-group partials -> per-row lse -> loss = sum(lse - tgt)/Tdec
// ---------------------------------------------------------------------------
__global__ __launch_bounds__(256) void loss_kernel(
    const float* __restrict__ pmax, const float* __restrict__ psum,
    const float* __restrict__ tgt_logit, float* __restrict__ out)
{
    const int tid = threadIdx.x;
    float local = 0.0f;
    for (int m = tid; m < 1024; m += 256) {
        float M = -INFINITY;
        for (int cg = 0; cg < NCG; cg++) M = fmaxf(M, pmax[cg * 1024 + m]);
        float S = 0.0f;
        for (int cg = 0; cg < NCG; cg++) S += psum[cg * 1024 + m] * expf(pmax[cg * 1024 + m] - M);
        local += M + logf(S) - tgt_logit[m];
    }
    __shared__ float red[256];
    red[tid] = local;
    __syncthreads();
    for (int s = 128; s > 0; s >>= 1) {
        if (tid < s) red[tid] += red[tid + s];
        __syncthreads();
    }
    if (tid == 0) out[0] = red[0] / (float)TDEC;
}

// ---------------------------------------------------------------------------
extern "C" void kernel_launch(void* const* d_in, const int* in_sizes, int n_in,
                              void* d_out, int out_size, void* d_ws, size_t ws_size,
                              hipStream_t stream)
{
    const int*   cw     = (const int*)  d_in[0];
    const int*   qw     = (const int*)  d_in[1];
    const float* emb_e  = (const float*)d_in[2];
    const float* emb_d  = (const float*)d_in[3];
    const float* Wih_e  = (const float*)d_in[4];
    const float* Whh_e  = (const float*)d_in[5];
    const float* bih_e  = (const float*)d_in[6];
    const float* bhh_e  = (const float*)d_in[7];
    const float* Wih_d  = (const float*)d_in[8];
    const float* Whh_d  = (const float*)d_in[9];
    const float* bih_d  = (const float*)d_in[10];
    const float* bhh_d  = (const float*)d_in[11];
    const float* Wg     = (const float*)d_in[12];
    const float* bg     = (const float*)d_in[13];

    // Workspace layout (floats); total ~65 MB
    float* ws      = (float*)d_ws;
    float* gx_enc  = ws;                                   // 8192*1536
    float* gx_dec  = gx_enc + (size_t)8192 * G3H;          // 1024*1536
    float* hbuf0   = gx_dec + (size_t)1024 * G3H;          // 32*512
    float* hbuf1   = hbuf0 + BB * HH;                      // 32*512
    float* h_all   = hbuf1 + BB * HH;                      // 1024*512
    float* pmax    = h_all + (size_t)1024 * HH;            // 49*1024
    float* psum    = pmax + NCG * 1024;                    // 49*1024
    float* tgt_l   = psum + NCG * 1024;                    // 1024
    float* WihT_e  = tgt_l + 1024;                         // 512*1536
    float* WihT_d  = WihT_e + (size_t)HH * G3H;            // 512*1536
    unsigned* bar  = (unsigned*)(WihT_d + (size_t)HH * G3H);  // 320 x u32 (tree)

    // h0 = 0; barrier counters = 0
    hipMemsetAsync(hbuf0, 0, BB * HH * sizeof(float), stream);
    hipMemsetAsync(bar, 0, 320 * sizeof(unsigned), stream);

    // Phase 0: weight transposes for the gx GEMMs
    transpose_w<<<dim3(16, 48), 256, 0, stream>>>(Wih_e, WihT_e);
    transpose_w<<<dim3(16, 48), 256, 0, stream>>>(Wih_d, WihT_d);

    // Phase 1: encoder + decoder gx (all timesteps in parallel)
    gxT_kernel<<<dim3(256, 2), 256, 0, stream>>>(cw, emb_e, WihT_e, bih_e, gx_enc, 0);
    gxT_kernel<<<dim3(32, 2),  256, 0, stream>>>(qw, emb_d, WihT_d, bih_d, gx_dec, 1);

    // Phase 2+4: the entire sequential scan (enc 256 + dec 32 steps) in ONE
    // persistent kernel; fence-free tree barrier + coherent (sc1) h exchange.
    scan_kernel<<<SCAN_NBLK, 256, 0, stream>>>(
        Whh_e, bhh_e, Whh_d, bhh_d, gx_enc, gx_dec, hbuf0, hbuf1, h_all, bar);

    // Phase 5: batched logits + online logsumexp partials (one big GEMM)
    logits_kernel<<<dim3(32, NCG), 256, 0, stream>>>(h_all, Wg, bg, qw, pmax, psum, tgt_l);

    // Phase 6: combine partials -> scalar loss
    loss_kernel<<<1, 256, 0, stream>>>(pmax, psum, tgt_l, (float*)d_out);
}